// Round 1
// baseline (545.853 us; speedup 1.0000x reference)
//
#include <hip/hip_runtime.h>

#define NB 8
#define NN 4096
#define KK 16
#define CC 128
#define NCOUT 256
#define E_IN 384          // original edge width
#define EK 352            // edge K after folding ppf_enc into e1
#define KS1 22            // EK / 16
#define KS2 16            // 256 / 16
#define EPS 1e-5f

#define WB1_ELEMS (KS1 * 8 * 64 * 8)   // 90112
#define WB2_ELEMS (KS2 * 8 * 64 * 8)   // 65536
#define WB2_OFF   (WB1_ELEMS * 2)
#define SMALL_OFF (WB1_ELEMS * 2 + WB2_ELEMS * 2)
// small f32 table layout (floats)
#define S_POSW 0      // 64x3 folded pos weights
#define S_POSB 192    // 64 folded pos bias
#define S_W1F 256     // 32x4 folded ppf layer1 weights
#define S_B1F 384     // 32 folded ppf layer1 bias
#define S_E1B 416     // 256 folded e1 bias (incl. ppf_b2 contribution)
#define S_E2B 672     // 256 folded e2 bias
#define SMALL_FLOATS 928

typedef __attribute__((ext_vector_type(8))) short bf16x8;
typedef __attribute__((ext_vector_type(16))) float f32x16;

static __device__ __forceinline__ unsigned short f2bf(float f) {
    unsigned u = __float_as_uint(f);
    u += 0x7fffu + ((u >> 16) & 1u);   // RNE
    return (unsigned short)(u >> 16);
}

// ---------------- prep: fold BN, pre-multiply ppf_w2 into e1_w, permute to MFMA B-frag order -----
__global__ void ppf_prep(
    const float* __restrict__ ppf_w1, const float* __restrict__ ppf_b1,
    const float* __restrict__ ppf_g,  const float* __restrict__ ppf_beta,
    const float* __restrict__ ppf_m,  const float* __restrict__ ppf_v,
    const float* __restrict__ ppf_w2, const float* __restrict__ ppf_b2,
    const float* __restrict__ pos_w,  const float* __restrict__ pos_b,
    const float* __restrict__ pos_g,  const float* __restrict__ pos_beta,
    const float* __restrict__ pos_m,  const float* __restrict__ pos_v,
    const float* __restrict__ e1_w,   const float* __restrict__ e1_b,
    const float* __restrict__ e1_g,   const float* __restrict__ e1_beta,
    const float* __restrict__ e1_m,   const float* __restrict__ e1_v,
    const float* __restrict__ e2_w,   const float* __restrict__ e2_b,
    const float* __restrict__ e2_g,   const float* __restrict__ e2_beta,
    const float* __restrict__ e2_m,   const float* __restrict__ e2_v,
    void* __restrict__ ws)
{
    int idx = blockIdx.x * 256 + threadIdx.x;
    unsigned short* wb1 = (unsigned short*)ws;
    unsigned short* wb2 = (unsigned short*)((char*)ws + WB2_OFF);
    float* sm = (float*)((char*)ws + SMALL_OFF);

    if (idx < WB1_ELEMS) {
        int t = idx >> 12;
        int c = (idx >> 9) & 7;
        int l = (idx >> 3) & 63;
        int j = idx & 7;
        int o = c * 32 + (l & 31);
        int i = t * 16 + ((l >> 5) << 3) + j;
        float s = e1_g[o] * rsqrtf(e1_v[o] + EPS);
        float v;
        if (i < 256) {
            v = e1_w[o * E_IN + i];                       // center/diff part
        } else if (i < 288) {
            int jj = i - 256;                             // combined (W_ppf @ ppf_w2)
            float a = 0.f;
            for (int p = 0; p < 64; ++p)
                a += e1_w[o * E_IN + 256 + p] * ppf_w2[p * 32 + jj];
            v = a;
        } else {
            v = e1_w[o * E_IN + (i + 32)];                // pos part (orig cols 320..383)
        }
        wb1[idx] = f2bf(v * s);
    } else if (idx < WB1_ELEMS + WB2_ELEMS) {
        int e = idx - WB1_ELEMS;
        int t = e >> 12;
        int c = (e >> 9) & 7;
        int l = (e >> 3) & 63;
        int j = e & 7;
        int o = c * 32 + (l & 31);
        int i = t * 16 + ((l >> 5) << 3) + j;
        float s = e2_g[o] * rsqrtf(e2_v[o] + EPS);
        wb2[e] = f2bf(e2_w[o * NCOUT + i] * s);
    } else if (idx < WB1_ELEMS + WB2_ELEMS + SMALL_FLOATS) {
        int s = idx - (WB1_ELEMS + WB2_ELEMS);
        float v;
        if (s < 192) {
            int o = s / 3, c2 = s - o * 3;
            float sc = pos_g[o] * rsqrtf(pos_v[o] + EPS);
            v = pos_w[o * 3 + c2] * sc;
        } else if (s < 256) {
            int o = s - 192;
            float sc = pos_g[o] * rsqrtf(pos_v[o] + EPS);
            v = (pos_b[o] - pos_m[o]) * sc + pos_beta[o];
        } else if (s < 384) {
            int q = s - 256; int j = q >> 2, i = q & 3;
            float sc = ppf_g[j] * rsqrtf(ppf_v[j] + EPS);
            v = ppf_w1[j * 4 + i] * sc;
        } else if (s < 416) {
            int j = s - 384;
            float sc = ppf_g[j] * rsqrtf(ppf_v[j] + EPS);
            v = (ppf_b1[j] - ppf_m[j]) * sc + ppf_beta[j];
        } else if (s < 672) {
            int o = s - 416;
            float sc = e1_g[o] * rsqrtf(e1_v[o] + EPS);
            float bb = e1_b[o];
            for (int p = 0; p < 64; ++p)
                bb += e1_w[o * E_IN + 256 + p] * ppf_b2[p];
            v = (bb - e1_m[o]) * sc + e1_beta[o];
        } else {
            int o = s - 672;
            float sc = e2_g[o] * rsqrtf(e2_v[o] + EPS);
            v = (e2_b[o] - e2_m[o]) * sc + e2_beta[o];
        }
        sm[s] = v;
    }
}

// ---------------- main fused kernel: 1 block = 4 (b,n) groups = 64 edge rows -----------------
__global__ __launch_bounds__(256, 3) void ppf_main(
    const float* __restrict__ kptf, const float* __restrict__ kptx,
    const float* __restrict__ nbrf, const float* __restrict__ nbrx,
    const float* __restrict__ nbrn, const void* __restrict__ ws,
    float* __restrict__ out)
{
    __shared__ __align__(16) char smem[64 * EK * 2];   // edge[64][352] bf16; reused as h[64][256] bf16
    __shared__ float rel_lds[64][4];
    __shared__ float smallw[SMALL_FLOATS];

    const int tid = threadIdx.x;
    const int lane = tid & 63;
    const int w = tid >> 6;
    const int l31 = lane & 31;
    const int h5 = lane >> 5;
    const long g0 = (long)blockIdx.x * 4;

    const unsigned short* wB1 = (const unsigned short*)ws;
    const unsigned short* wB2 = (const unsigned short*)((const char*)ws + WB2_OFF);
    const float* smallg = (const float*)((const char*)ws + SMALL_OFF);

    for (int i = tid; i < SMALL_FLOATS; i += 256) smallw[i] = smallg[i];

    // Phase C: center / diff  ->  edge cols [0,256)
    #pragma unroll
    for (int it = 0; it < 4; ++it) {
        int chunk = tid + it * 256;                 // 64 rows x 16 chunks
        int r = chunk >> 4, cj = chunk & 15;
        int gl = r >> 4, k = r & 15;
        long g = g0 + gl;
        const float4* cp = (const float4*)(kptf + g * CC + cj * 8);
        const float4* np = (const float4*)(nbrf + (g * KK + k) * CC + cj * 8);
        float4 c0 = cp[0], c1 = cp[1];
        float4 n0 = np[0], n1 = np[1];
        float cfv[8] = {c0.x, c0.y, c0.z, c0.w, c1.x, c1.y, c1.z, c1.w};
        float nfv[8] = {n0.x, n0.y, n0.z, n0.w, n1.x, n1.y, n1.z, n1.w};
        bf16x8 vc, vd;
        #pragma unroll
        for (int j = 0; j < 8; ++j) {
            vc[j] = (short)f2bf(cfv[j]);
            vd[j] = (short)f2bf(nfv[j] - cfv[j]);
        }
        int swz = (r & 7) << 4;
        *(bf16x8*)(smem + ((r * (EK * 2) + cj * 16) ^ swz)) = vc;
        *(bf16x8*)(smem + ((r * (EK * 2) + 256 + cj * 16) ^ swz)) = vd;
    }
    __syncthreads();

    // Phase A (wave 0): geometry + ppf layer-1  ->  h1 into edge cols [256,288)
    if (w == 0) {
        int r = lane, gl = r >> 4, k = r & 15;
        long g = g0 + gl;
        const float* nxp = nbrx + (g * KK + k) * 3;
        const float* kxp = kptx + g * 3;
        const float* nnp = nbrn + (g * KK + k) * 3;
        float rx = nxp[0] - kxp[0], ry = nxp[1] - kxp[1], rz = nxp[2] - kxp[2];
        float ax = nnp[0], ay = nnp[1], az = nnp[2];
        rel_lds[r][0] = rx; rel_lds[r][1] = ry; rel_lds[r][2] = rz;
        float sx = ax, sy = ay, sz = az;
        #pragma unroll
        for (int m = 1; m < 16; m <<= 1) {
            sx += __shfl_xor(sx, m);
            sy += __shfl_xor(sy, m);
            sz += __shfl_xor(sz, m);
        }
        sx *= 0.0625f; sy *= 0.0625f; sz *= 0.0625f;
        float kl = fmaxf(sqrtf(sx * sx + sy * sy + sz * sz), 1e-12f);
        float inv = 1.0f / kl;
        float knx = sx * inv, kny = sy * inv, knz = sz * inv;
        float dn = sqrtf(rx * rx + ry * ry + rz * rz);
        float di = 1.0f / (dn + 1e-8f);
        float dx = rx * di, dy = ry * di, dz = rz * di;
        float alpha = fminf(fmaxf(knx * dx + kny * dy + knz * dz, -1.f), 1.f);
        float phi   = fminf(fmaxf(ax * dx + ay * dy + az * dz, -1.f), 1.f);
        float theta = fminf(fmaxf(knx * ax + kny * ay + knz * az, -1.f), 1.f);
        int swz = (r & 7) << 4;
        #pragma unroll
        for (int q = 0; q < 4; ++q) {
            bf16x8 hv;
            #pragma unroll
            for (int u = 0; u < 8; ++u) {
                int j = q * 8 + u;
                const float* wr = &smallw[S_W1F + j * 4];
                float v = dn * wr[0] + alpha * wr[1] + phi * wr[2] + theta * wr[3]
                          + smallw[S_B1F + j];
                hv[u] = (short)f2bf(fmaxf(v, 0.f));
            }
            *(bf16x8*)(smem + ((r * (EK * 2) + 512 + q * 16) ^ swz)) = hv;
        }
    }
    __syncthreads();

    // Phase B: pos_enc  ->  edge cols [288,352)
    {
        int col = tid & 63;
        int rbase = tid >> 6;
        float w0 = smallw[S_POSW + col * 3];
        float w1 = smallw[S_POSW + col * 3 + 1];
        float w2v = smallw[S_POSW + col * 3 + 2];
        float pb = smallw[S_POSB + col];
        #pragma unroll
        for (int i = 0; i < 16; ++i) {
            int r = rbase + i * 4;
            float v = fmaxf(rel_lds[r][0] * w0 + rel_lds[r][1] * w1 + rel_lds[r][2] * w2v + pb, 0.f);
            *(unsigned short*)(smem + ((r * (EK * 2) + 576 + col * 2) ^ ((r & 7) << 4))) = f2bf(v);
        }
    }
    __syncthreads();

    // GEMM1: edge[64][352] @ W1'^T -> acc (per wave: rows 0..63, cols w*64..w*64+63)
    f32x16 acc[2][2];
    #pragma unroll
    for (int a = 0; a < 2; ++a)
        #pragma unroll
        for (int b = 0; b < 2; ++b)
            #pragma unroll
            for (int q = 0; q < 16; ++q) acc[a][b][q] = 0.f;

    {
        const int kofs = h5 << 4;
        for (int t = 0; t < KS1; ++t) {
            int r0 = l31, r1 = 32 + l31;
            bf16x8 a0 = *(const bf16x8*)(smem + ((r0 * (EK * 2) + t * 32 + kofs) ^ ((r0 & 7) << 4)));
            bf16x8 a1 = *(const bf16x8*)(smem + ((r1 * (EK * 2) + t * 32 + kofs) ^ ((r1 & 7) << 4)));
            const unsigned short* wp = wB1 + (size_t)((t * 8 + 2 * w) * 64 + lane) * 8;
            bf16x8 b0 = *(const bf16x8*)wp;
            bf16x8 b1 = *(const bf16x8*)(wp + 512);
            acc[0][0] = __builtin_amdgcn_mfma_f32_32x32x16_bf16(a0, b0, acc[0][0], 0, 0, 0);
            acc[0][1] = __builtin_amdgcn_mfma_f32_32x32x16_bf16(a0, b1, acc[0][1], 0, 0, 0);
            acc[1][0] = __builtin_amdgcn_mfma_f32_32x32x16_bf16(a1, b0, acc[1][0], 0, 0, 0);
            acc[1][1] = __builtin_amdgcn_mfma_f32_32x32x16_bf16(a1, b1, acc[1][1], 0, 0, 0);
        }
    }
    __syncthreads();

    // Epilogue 1: h = relu(acc + b1') -> smem as h[64][256] bf16 (swizzled)
    #pragma unroll
    for (int rf = 0; rf < 2; ++rf)
        #pragma unroll
        for (int cf = 0; cf < 2; ++cf) {
            int c = (2 * w + cf) * 32 + l31;
            float bias = smallw[S_E1B + c];
            #pragma unroll
            for (int reg = 0; reg < 16; ++reg) {
                int row = rf * 32 + (reg & 3) + ((reg >> 2) << 3) + (h5 << 2);
                float v = fmaxf(acc[rf][cf][reg] + bias, 0.f);
                *(unsigned short*)(smem + ((row * 512 + c * 2) ^ ((row & 7) << 4))) = f2bf(v);
            }
        }
    __syncthreads();

    // GEMM2: h[64][256] @ W2'^T
    #pragma unroll
    for (int a = 0; a < 2; ++a)
        #pragma unroll
        for (int b = 0; b < 2; ++b)
            #pragma unroll
            for (int q = 0; q < 16; ++q) acc[a][b][q] = 0.f;
    {
        const int kofs = h5 << 4;
        for (int t = 0; t < KS2; ++t) {
            int r0 = l31, r1 = 32 + l31;
            bf16x8 a0 = *(const bf16x8*)(smem + ((r0 * 512 + t * 32 + kofs) ^ ((r0 & 7) << 4)));
            bf16x8 a1 = *(const bf16x8*)(smem + ((r1 * 512 + t * 32 + kofs) ^ ((r1 & 7) << 4)));
            const unsigned short* wp = wB2 + (size_t)((t * 8 + 2 * w) * 64 + lane) * 8;
            bf16x8 b0 = *(const bf16x8*)wp;
            bf16x8 b1 = *(const bf16x8*)(wp + 512);
            acc[0][0] = __builtin_amdgcn_mfma_f32_32x32x16_bf16(a0, b0, acc[0][0], 0, 0, 0);
            acc[0][1] = __builtin_amdgcn_mfma_f32_32x32x16_bf16(a0, b1, acc[0][1], 0, 0, 0);
            acc[1][0] = __builtin_amdgcn_mfma_f32_32x32x16_bf16(a1, b0, acc[1][0], 0, 0, 0);
            acc[1][1] = __builtin_amdgcn_mfma_f32_32x32x16_bf16(a1, b1, acc[1][1], 0, 0, 0);
        }
    }

    // Epilogue 2: bias + relu + max over k (16 rows per group) + store
    #pragma unroll
    for (int rf = 0; rf < 2; ++rf)
        #pragma unroll
        for (int cf = 0; cf < 2; ++cf) {
            int c = (2 * w + cf) * 32 + l31;
            float bias = smallw[S_E2B + c];
            #pragma unroll
            for (int gs = 0; gs < 2; ++gs) {
                float m = acc[rf][cf][gs * 8];
                #pragma unroll
                for (int q = 1; q < 8; ++q) m = fmaxf(m, acc[rf][cf][gs * 8 + q]);
                m = fmaxf(m + bias, 0.f);
                m = fmaxf(m, __shfl_xor(m, 32));
                if (lane < 32) {
                    long g = g0 + rf * 2 + gs;
                    out[g * NCOUT + c] = m;
                }
            }
        }
}

extern "C" void kernel_launch(void* const* d_in, const int* in_sizes, int n_in,
                              void* d_out, int out_size, void* d_ws, size_t ws_size,
                              hipStream_t stream)
{
    const float* kptf = (const float*)d_in[0];
    const float* kptx = (const float*)d_in[1];
    const float* nbrf = (const float*)d_in[2];
    const float* nbrx = (const float*)d_in[3];
    const float* nbrn = (const float*)d_in[4];

    int prep_total = WB1_ELEMS + WB2_ELEMS + SMALL_FLOATS;
    ppf_prep<<<dim3((prep_total + 255) / 256), dim3(256), 0, stream>>>(
        (const float*)d_in[5],  (const float*)d_in[6],  (const float*)d_in[7],
        (const float*)d_in[8],  (const float*)d_in[9],  (const float*)d_in[10],
        (const float*)d_in[11], (const float*)d_in[12], (const float*)d_in[13],
        (const float*)d_in[14], (const float*)d_in[15], (const float*)d_in[16],
        (const float*)d_in[17], (const float*)d_in[18], (const float*)d_in[19],
        (const float*)d_in[20], (const float*)d_in[21], (const float*)d_in[22],
        (const float*)d_in[23], (const float*)d_in[24], (const float*)d_in[25],
        (const float*)d_in[26], (const float*)d_in[27], (const float*)d_in[28],
        (const float*)d_in[29], (const float*)d_in[30], d_ws);

    ppf_main<<<dim3((NB * NN) / 4), dim3(256), 0, stream>>>(
        kptf, kptx, nbrf, nbrx, nbrn, d_ws, (float*)d_out);
}

// Round 3
// 530.690 us; speedup vs baseline: 1.0286x; 1.0286x over previous
//
#include <hip/hip_runtime.h>

#define NB 8
#define NN 4096
#define KK 16
#define CC 128
#define NCOUT 256
#define E_IN 384
#define KS1 14            // GEMM1 K = 224 (nbrf 128 | ppf-h1 32 | pos 64)
#define KS2 16            // GEMM2 K = 256
#define KSC 8             // Cc GEMM K = 128
#define EPS 1e-5f

#define WB1_ELEMS (KS1 * 8 * 64 * 8)   // 57344
#define WB2_ELEMS (KS2 * 8 * 64 * 8)   // 65536
#define WCC_ELEMS (KSC * 8 * 64 * 8)   // 32768
#define WB2_OFF   (WB1_ELEMS * 2)
#define WCC_OFF   (WB2_OFF + WB2_ELEMS * 2)
#define SMALL_OFF (WCC_OFF + WCC_ELEMS * 2)
// small f32 table (floats)
#define S_POSW 0      // 64x3 folded pos weights
#define S_POSB 192    // 64 folded pos bias
#define S_W1F 256     // 32x4 folded ppf layer1 weights
#define S_B1F 384     // 32 folded ppf layer1 bias
#define S_E2B 416     // 256 folded e2 bias
#define S_E1B 672     // 256 folded e1 bias (incl ppf_b2 term) -> folded into Cc
#define SMALL_FLOATS 928

typedef __attribute__((ext_vector_type(8))) short bf16x8;
typedef __attribute__((ext_vector_type(16))) float f32x16;

static __device__ __forceinline__ unsigned short f2bf(float f) {
    unsigned u = __float_as_uint(f);
    u += 0x7fffu + ((u >> 16) & 1u);   // RNE
    return (unsigned short)(u >> 16);
}

// ---------------- prep: fold BN into weights, build MFMA-B-fragment-permuted buffers ----------
__global__ void ppf_prep(
    const float* __restrict__ ppf_w1, const float* __restrict__ ppf_b1,
    const float* __restrict__ ppf_g,  const float* __restrict__ ppf_beta,
    const float* __restrict__ ppf_m,  const float* __restrict__ ppf_v,
    const float* __restrict__ ppf_w2, const float* __restrict__ ppf_b2,
    const float* __restrict__ pos_w,  const float* __restrict__ pos_b,
    const float* __restrict__ pos_g,  const float* __restrict__ pos_beta,
    const float* __restrict__ pos_m,  const float* __restrict__ pos_v,
    const float* __restrict__ e1_w,   const float* __restrict__ e1_b,
    const float* __restrict__ e1_g,   const float* __restrict__ e1_beta,
    const float* __restrict__ e1_m,   const float* __restrict__ e1_v,
    const float* __restrict__ e2_w,   const float* __restrict__ e2_b,
    const float* __restrict__ e2_g,   const float* __restrict__ e2_beta,
    const float* __restrict__ e2_m,   const float* __restrict__ e2_v,
    void* __restrict__ ws)
{
    int idx = blockIdx.x * 256 + threadIdx.x;
    unsigned short* wb1 = (unsigned short*)ws;
    unsigned short* wb2 = (unsigned short*)((char*)ws + WB2_OFF);
    unsigned short* wcc = (unsigned short*)((char*)ws + WCC_OFF);
    float* sm = (float*)((char*)ws + SMALL_OFF);

    if (idx < WB1_ELEMS) {
        int t = idx >> 12, c = (idx >> 9) & 7, l = (idx >> 3) & 63, j = idx & 7;
        int o = c * 32 + (l & 31);
        int i = t * 16 + ((l >> 5) << 3) + j;        // 0..223
        float s = e1_g[o] * rsqrtf(e1_v[o] + EPS);
        float v;
        if (i < 128) {
            v = e1_w[o * E_IN + 128 + i];            // Wd (diff weights) for nbrf
        } else if (i < 160) {
            int q = i - 128;                          // combined (W_e1,ppf @ ppf_w2)
            float a = 0.f;
            for (int p = 0; p < 64; ++p)
                a += e1_w[o * E_IN + 256 + p] * ppf_w2[p * 32 + q];
            v = a;
        } else {
            v = e1_w[o * E_IN + 160 + i];            // pos part: orig cols 320..383
        }
        wb1[idx] = f2bf(v * s);
    } else if (idx < WB1_ELEMS + WB2_ELEMS) {
        int e = idx - WB1_ELEMS;
        int t = e >> 12, c = (e >> 9) & 7, l = (e >> 3) & 63, j = e & 7;
        int o = c * 32 + (l & 31);
        int i = t * 16 + ((l >> 5) << 3) + j;
        float s = e2_g[o] * rsqrtf(e2_v[o] + EPS);
        wb2[e] = f2bf(e2_w[o * NCOUT + i] * s);
    } else if (idx < WB1_ELEMS + WB2_ELEMS + WCC_ELEMS) {
        int e = idx - (WB1_ELEMS + WB2_ELEMS);
        int t = e >> 12, c = (e >> 9) & 7, l = (e >> 3) & 63, j = e & 7;
        int o = c * 32 + (l & 31);
        int i = t * 16 + ((l >> 5) << 3) + j;        // 0..127
        float s = e1_g[o] * rsqrtf(e1_v[o] + EPS);
        wcc[e] = f2bf((e1_w[o * E_IN + i] - e1_w[o * E_IN + 128 + i]) * s);  // Wc - Wd
    } else if (idx < WB1_ELEMS + WB2_ELEMS + WCC_ELEMS + SMALL_FLOATS) {
        int s = idx - (WB1_ELEMS + WB2_ELEMS + WCC_ELEMS);
        float v;
        if (s < 192) {
            int o = s / 3, c2 = s - o * 3;
            v = pos_w[o * 3 + c2] * (pos_g[o] * rsqrtf(pos_v[o] + EPS));
        } else if (s < 256) {
            int o = s - 192;
            float sc = pos_g[o] * rsqrtf(pos_v[o] + EPS);
            v = (pos_b[o] - pos_m[o]) * sc + pos_beta[o];
        } else if (s < 384) {
            int q = s - 256; int j = q >> 2, i = q & 3;
            v = ppf_w1[j * 4 + i] * (ppf_g[j] * rsqrtf(ppf_v[j] + EPS));
        } else if (s < 416) {
            int j = s - 384;
            float sc = ppf_g[j] * rsqrtf(ppf_v[j] + EPS);
            v = (ppf_b1[j] - ppf_m[j]) * sc + ppf_beta[j];
        } else if (s < 672) {
            int o = s - 416;
            float sc = e2_g[o] * rsqrtf(e2_v[o] + EPS);
            v = (e2_b[o] - e2_m[o]) * sc + e2_beta[o];
        } else {
            int o = s - 672;
            float sc = e1_g[o] * rsqrtf(e1_v[o] + EPS);
            float bb = e1_b[o];
            for (int p = 0; p < 64; ++p)
                bb += e1_w[o * E_IN + 256 + p] * ppf_b2[p];
            v = (bb - e1_m[o]) * sc + e1_beta[o];
        }
        sm[s] = v;
    }
}

// ---------------- Cc GEMM: out[g][:] = kptf[g] @ (Wc-Wd)'^T + e1_bias'  (per point) -----------
__global__ __launch_bounds__(256, 3) void cc_gemm(
    const float* __restrict__ kptf, const void* __restrict__ ws, float* __restrict__ out)
{
    __shared__ __align__(16) char smem[64 * 256];   // kpt tile [64][128] bf16, swizzled
    const int tid = threadIdx.x;
    const int lane = tid & 63;
    const int w = tid >> 6;
    const int l31 = lane & 31, h5 = lane >> 5;
    const long p0 = (long)blockIdx.x * 64;
    const unsigned short* wCC = (const unsigned short*)((const char*)ws + WCC_OFF);
    const float* smallg = (const float*)((const char*)ws + SMALL_OFF);

    // stage kptf tile -> bf16 LDS
    {
        int r = tid >> 2, q = tid & 3;
        const float4* kp = (const float4*)(kptf + (p0 + r) * CC + q * 32);
        float4 kf[8];
        #pragma unroll
        for (int u = 0; u < 8; ++u) kf[u] = kp[u];
        int base = r * 256, swz = (r & 7) << 4;
        #pragma unroll
        for (int u2 = 0; u2 < 4; ++u2) {
            bf16x8 v;
            const float4 f0 = kf[2 * u2], f1 = kf[2 * u2 + 1];
            v[0] = (short)f2bf(f0.x); v[1] = (short)f2bf(f0.y);
            v[2] = (short)f2bf(f0.z); v[3] = (short)f2bf(f0.w);
            v[4] = (short)f2bf(f1.x); v[5] = (short)f2bf(f1.y);
            v[6] = (short)f2bf(f1.z); v[7] = (short)f2bf(f1.w);
            *(bf16x8*)(smem + ((base + q * 64 + u2 * 16) ^ swz)) = v;
        }
    }
    float bias0 = smallg[S_E1B + (2 * w + 0) * 32 + l31];
    float bias1 = smallg[S_E1B + (2 * w + 1) * 32 + l31];
    __syncthreads();

    f32x16 acc[2][2];
    #pragma unroll
    for (int rf = 0; rf < 2; ++rf) {
        #pragma unroll
        for (int q = 0; q < 16; ++q) { acc[rf][0][q] = bias0; acc[rf][1][q] = bias1; }
    }

    const int a0base = l31 * 256 + h5 * 16;
    const int a1base = (32 + l31) * 256 + h5 * 16;
    const int aswz = (l31 & 7) << 4;
    const unsigned short* wp = wCC + (size_t)(2 * w * 64 + lane) * 8;

    bf16x8 a0 = *(const bf16x8*)(smem + (a0base ^ aswz));
    bf16x8 a1 = *(const bf16x8*)(smem + (a1base ^ aswz));
    bf16x8 b0 = *(const bf16x8*)wp;
    bf16x8 b1 = *(const bf16x8*)(wp + 512);
    #pragma unroll 2
    for (int t = 0; t < KSC - 1; ++t) {
        bf16x8 a0n = *(const bf16x8*)(smem + ((a0base + (t + 1) * 32) ^ aswz));
        bf16x8 a1n = *(const bf16x8*)(smem + ((a1base + (t + 1) * 32) ^ aswz));
        const unsigned short* wpn = wp + (size_t)(t + 1) * 4096;
        bf16x8 b0n = *(const bf16x8*)wpn;
        bf16x8 b1n = *(const bf16x8*)(wpn + 512);
        acc[0][0] = __builtin_amdgcn_mfma_f32_32x32x16_bf16(a0, b0, acc[0][0], 0, 0, 0);
        acc[0][1] = __builtin_amdgcn_mfma_f32_32x32x16_bf16(a0, b1, acc[0][1], 0, 0, 0);
        acc[1][0] = __builtin_amdgcn_mfma_f32_32x32x16_bf16(a1, b0, acc[1][0], 0, 0, 0);
        acc[1][1] = __builtin_amdgcn_mfma_f32_32x32x16_bf16(a1, b1, acc[1][1], 0, 0, 0);
        a0 = a0n; a1 = a1n; b0 = b0n; b1 = b1n;
    }
    acc[0][0] = __builtin_amdgcn_mfma_f32_32x32x16_bf16(a0, b0, acc[0][0], 0, 0, 0);
    acc[0][1] = __builtin_amdgcn_mfma_f32_32x32x16_bf16(a0, b1, acc[0][1], 0, 0, 0);
    acc[1][0] = __builtin_amdgcn_mfma_f32_32x32x16_bf16(a1, b0, acc[1][0], 0, 0, 0);
    acc[1][1] = __builtin_amdgcn_mfma_f32_32x32x16_bf16(a1, b1, acc[1][1], 0, 0, 0);

    #pragma unroll
    for (int rf = 0; rf < 2; ++rf)
        #pragma unroll
        for (int cf = 0; cf < 2; ++cf) {
            int c = (2 * w + cf) * 32 + l31;
            #pragma unroll
            for (int reg = 0; reg < 16; ++reg) {
                int row = rf * 32 + (reg & 3) + ((reg >> 2) << 3) + (h5 << 2);
                out[(p0 + row) * NCOUT + c] = acc[rf][cf][reg];
            }
        }
}

// ---------------- main fused kernel: 1 block = 4 (b,n) groups = 64 edge rows ------------------
__global__ __launch_bounds__(256, 3) void ppf_main(
    const float* __restrict__ kptx, const float* __restrict__ nbrf,
    const float* __restrict__ nbrx, const float* __restrict__ nbrn,
    const void* __restrict__ ws, float* out)
{
    __shared__ __align__(16) char smem[64 * 512];   // edge[64][448B] / h[64][512B] (aliased)
    __shared__ float rel_lds[64][4];

    const int tid = threadIdx.x;
    const int lane = tid & 63;
    const int w = tid >> 6;
    const int l31 = lane & 31, h5 = lane >> 5;
    const long g0 = (long)blockIdx.x * 4;

    const unsigned short* wB1 = (const unsigned short*)ws;
    const unsigned short* wB2 = (const unsigned short*)((const char*)ws + WB2_OFF);
    const float* smallg = (const float*)((const char*)ws + SMALL_OFF);

    // ---- Phase C global loads (issue first): nbrf tile, 64 rows x 128 cols
    const int cr = tid >> 2, cq = tid & 3;
    const long cg = g0 + (cr >> 4);
    const float4* nfp = (const float4*)(nbrf + (cg * KK + (cr & 15)) * CC + cq * 32);
    float4 nf[8];
    #pragma unroll
    for (int u = 0; u < 8; ++u) nf[u] = nfp[u];

    // ---- Cc accumulator-init loads (from d_out, produced by cc_gemm)
    float ccv[2][2][2];
    #pragma unroll
    for (int rf = 0; rf < 2; ++rf)
        #pragma unroll
        for (int cf = 0; cf < 2; ++cf)
            #pragma unroll
            for (int hf = 0; hf < 2; ++hf)
                ccv[rf][cf][hf] = out[(g0 + 2 * rf + hf) * NCOUT + (2 * w + cf) * 32 + l31];

    // ---- pos-encoder weights (per-lane column)
    float pw0 = smallg[S_POSW + lane * 3];
    float pw1 = smallg[S_POSW + lane * 3 + 1];
    float pw2 = smallg[S_POSW + lane * 3 + 2];
    float pb  = smallg[S_POSB + lane];

    // ---- Phase A: geometry + ppf layer-1 (each wave owns one group; lanes 4x-duplicated)
    {
        const long g = g0 + w;
        const int k = lane & 15;
        const int r = w * 16 + k;
        const float* nxp = nbrx + (g * KK + k) * 3;
        const float* nnp = nbrn + (g * KK + k) * 3;
        float kx0 = kptx[g * 3], kx1 = kptx[g * 3 + 1], kx2 = kptx[g * 3 + 2];
        float rx = nxp[0] - kx0, ry = nxp[1] - kx1, rz = nxp[2] - kx2;
        float ax = nnp[0], ay = nnp[1], az = nnp[2];
        rel_lds[r][0] = rx; rel_lds[r][1] = ry; rel_lds[r][2] = rz;
        float sx = ax, sy = ay, sz = az;
        #pragma unroll
        for (int m = 1; m < 16; m <<= 1) {
            sx += __shfl_xor(sx, m); sy += __shfl_xor(sy, m); sz += __shfl_xor(sz, m);
        }
        sx *= 0.0625f; sy *= 0.0625f; sz *= 0.0625f;
        float kl = fmaxf(sqrtf(sx * sx + sy * sy + sz * sz), 1e-12f);
        float inv = 1.0f / kl;
        float knx = sx * inv, kny = sy * inv, knz = sz * inv;
        float dn = sqrtf(rx * rx + ry * ry + rz * rz);
        float di = 1.0f / (dn + 1e-8f);
        float dx = rx * di, dy = ry * di, dz = rz * di;
        float alpha = fminf(fmaxf(knx * dx + kny * dy + knz * dz, -1.f), 1.f);
        float phi   = fminf(fmaxf(ax * dx + ay * dy + az * dz, -1.f), 1.f);
        float theta = fminf(fmaxf(knx * ax + kny * ay + knz * az, -1.f), 1.f);
        int base = r * 448, swz = (r & 7) << 4;
        #pragma unroll
        for (int q = 0; q < 4; ++q) {
            bf16x8 hv;
            #pragma unroll
            for (int u = 0; u < 8; ++u) {
                int j = q * 8 + u;
                float v = dn    * smallg[S_W1F + j * 4]
                        + alpha * smallg[S_W1F + j * 4 + 1]
                        + phi   * smallg[S_W1F + j * 4 + 2]
                        + theta * smallg[S_W1F + j * 4 + 3]
                        + smallg[S_B1F + j];
                hv[u] = (short)f2bf(fmaxf(v, 0.f));
            }
            *(bf16x8*)(smem + ((base + 256 + q * 16) ^ swz)) = hv;
        }
    }

    // ---- Phase C stores: nbrf -> bf16 edge cols [0,128)
    {
        int base = cr * 448, swz = (cr & 7) << 4;
        #pragma unroll
        for (int u2 = 0; u2 < 4; ++u2) {
            bf16x8 v;
            const float4 f0 = nf[2 * u2], f1 = nf[2 * u2 + 1];
            v[0] = (short)f2bf(f0.x); v[1] = (short)f2bf(f0.y);
            v[2] = (short)f2bf(f0.z); v[3] = (short)f2bf(f0.w);
            v[4] = (short)f2bf(f1.x); v[5] = (short)f2bf(f1.y);
            v[6] = (short)f2bf(f1.z); v[7] = (short)f2bf(f1.w);
            *(bf16x8*)(smem + ((base + cq * 64 + u2 * 16) ^ swz)) = v;
        }
    }
    __syncthreads();

    // ---- Phase B: pos_enc -> edge cols [160,224)  (colbytes 320..447)
    {
        #pragma unroll
        for (int i = 0; i < 16; ++i) {
            int r = w + i * 4;
            float v = fmaxf(rel_lds[r][0] * pw0 + rel_lds[r][1] * pw1 + rel_lds[r][2] * pw2 + pb, 0.f);
            *(unsigned short*)(smem + ((r * 448 + 320 + lane * 2) ^ ((r & 7) << 4))) = f2bf(v);
        }
    }
    __syncthreads();

    // ---- GEMM1: K=224, acc initialized from Cc (center contribution + e1 bias)
    f32x16 acc[2][2];
    #pragma unroll
    for (int rf = 0; rf < 2; ++rf)
        #pragma unroll
        for (int cf = 0; cf < 2; ++cf)
            #pragma unroll
            for (int q = 0; q < 16; ++q)
                acc[rf][cf][q] = ccv[rf][cf][q >> 3];

    {
        const int a0base = l31 * 448 + h5 * 16;
        const int a1base = (32 + l31) * 448 + h5 * 16;
        const int aswz = (l31 & 7) << 4;
        const unsigned short* wp = wB1 + (size_t)(2 * w * 64 + lane) * 8;
        bf16x8 a0 = *(const bf16x8*)(smem + (a0base ^ aswz));
        bf16x8 a1 = *(const bf16x8*)(smem + (a1base ^ aswz));
        bf16x8 b0 = *(const bf16x8*)wp;
        bf16x8 b1 = *(const bf16x8*)(wp + 512);
        #pragma unroll 2
        for (int t = 0; t < KS1 - 1; ++t) {
            bf16x8 a0n = *(const bf16x8*)(smem + ((a0base + (t + 1) * 32) ^ aswz));
            bf16x8 a1n = *(const bf16x8*)(smem + ((a1base + (t + 1) * 32) ^ aswz));
            const unsigned short* wpn = wp + (size_t)(t + 1) * 4096;
            bf16x8 b0n = *(const bf16x8*)wpn;
            bf16x8 b1n = *(const bf16x8*)(wpn + 512);
            acc[0][0] = __builtin_amdgcn_mfma_f32_32x32x16_bf16(a0, b0, acc[0][0], 0, 0, 0);
            acc[0][1] = __builtin_amdgcn_mfma_f32_32x32x16_bf16(a0, b1, acc[0][1], 0, 0, 0);
            acc[1][0] = __builtin_amdgcn_mfma_f32_32x32x16_bf16(a1, b0, acc[1][0], 0, 0, 0);
            acc[1][1] = __builtin_amdgcn_mfma_f32_32x32x16_bf16(a1, b1, acc[1][1], 0, 0, 0);
            a0 = a0n; a1 = a1n; b0 = b0n; b1 = b1n;
        }
        acc[0][0] = __builtin_amdgcn_mfma_f32_32x32x16_bf16(a0, b0, acc[0][0], 0, 0, 0);
        acc[0][1] = __builtin_amdgcn_mfma_f32_32x32x16_bf16(a0, b1, acc[0][1], 0, 0, 0);
        acc[1][0] = __builtin_amdgcn_mfma_f32_32x32x16_bf16(a1, b0, acc[1][0], 0, 0, 0);
        acc[1][1] = __builtin_amdgcn_mfma_f32_32x32x16_bf16(a1, b1, acc[1][1], 0, 0, 0);
    }
    __syncthreads();

    // ---- Epilogue 1: h = relu(acc)  (bias already in Cc) -> smem h[64][256] bf16
    #pragma unroll
    for (int rf = 0; rf < 2; ++rf)
        #pragma unroll
        for (int cf = 0; cf < 2; ++cf) {
            int c = (2 * w + cf) * 32 + l31;
            #pragma unroll
            for (int reg = 0; reg < 16; ++reg) {
                int row = rf * 32 + (reg & 3) + ((reg >> 2) << 3) + (h5 << 2);
                *(unsigned short*)(smem + ((row * 512 + c * 2) ^ ((row & 7) << 4))) =
                    f2bf(fmaxf(acc[rf][cf][reg], 0.f));
            }
        }
    __syncthreads();

    // ---- GEMM2: K=256
    #pragma unroll
    for (int rf = 0; rf < 2; ++rf)
        #pragma unroll
        for (int cf = 0; cf < 2; ++cf)
            #pragma unroll
            for (int q = 0; q < 16; ++q)
                acc[rf][cf][q] = 0.f;
    {
        const int a0base = l31 * 512 + h5 * 16;
        const int a1base = (32 + l31) * 512 + h5 * 16;
        const int aswz = (l31 & 7) << 4;
        const unsigned short* wp = wB2 + (size_t)(2 * w * 64 + lane) * 8;
        bf16x8 a0 = *(const bf16x8*)(smem + (a0base ^ aswz));
        bf16x8 a1 = *(const bf16x8*)(smem + (a1base ^ aswz));
        bf16x8 b0 = *(const bf16x8*)wp;
        bf16x8 b1 = *(const bf16x8*)(wp + 512);
        #pragma unroll 2
        for (int t = 0; t < KS2 - 1; ++t) {
            bf16x8 a0n = *(const bf16x8*)(smem + ((a0base + (t + 1) * 32) ^ aswz));
            bf16x8 a1n = *(const bf16x8*)(smem + ((a1base + (t + 1) * 32) ^ aswz));
            const unsigned short* wpn = wp + (size_t)(t + 1) * 4096;
            bf16x8 b0n = *(const bf16x8*)wpn;
            bf16x8 b1n = *(const bf16x8*)(wpn + 512);
            acc[0][0] = __builtin_amdgcn_mfma_f32_32x32x16_bf16(a0, b0, acc[0][0], 0, 0, 0);
            acc[0][1] = __builtin_amdgcn_mfma_f32_32x32x16_bf16(a0, b1, acc[0][1], 0, 0, 0);
            acc[1][0] = __builtin_amdgcn_mfma_f32_32x32x16_bf16(a1, b0, acc[1][0], 0, 0, 0);
            acc[1][1] = __builtin_amdgcn_mfma_f32_32x32x16_bf16(a1, b1, acc[1][1], 0, 0, 0);
            a0 = a0n; a1 = a1n; b0 = b0n; b1 = b1n;
        }
        acc[0][0] = __builtin_amdgcn_mfma_f32_32x32x16_bf16(a0, b0, acc[0][0], 0, 0, 0);
        acc[0][1] = __builtin_amdgcn_mfma_f32_32x32x16_bf16(a0, b1, acc[0][1], 0, 0, 0);
        acc[1][0] = __builtin_amdgcn_mfma_f32_32x32x16_bf16(a1, b0, acc[1][0], 0, 0, 0);
        acc[1][1] = __builtin_amdgcn_mfma_f32_32x32x16_bf16(a1, b1, acc[1][1], 0, 0, 0);
    }

    // ---- Epilogue 2: bias + relu + max over k + store
    #pragma unroll
    for (int rf = 0; rf < 2; ++rf)
        #pragma unroll
        for (int cf = 0; cf < 2; ++cf) {
            int c = (2 * w + cf) * 32 + l31;
            float bias = smallg[S_E2B + c];
            #pragma unroll
            for (int gs = 0; gs < 2; ++gs) {
                float m = acc[rf][cf][gs * 8];
                #pragma unroll
                for (int q = 1; q < 8; ++q) m = fmaxf(m, acc[rf][cf][gs * 8 + q]);
                m = fmaxf(m + bias, 0.f);
                m = fmaxf(m, __shfl_xor(m, 32));
                if (lane < 32) {
                    long g = g0 + rf * 2 + gs;
                    out[g * NCOUT + c] = m;
                }
            }
        }
}

extern "C" void kernel_launch(void* const* d_in, const int* in_sizes, int n_in,
                              void* d_out, int out_size, void* d_ws, size_t ws_size,
                              hipStream_t stream)
{
    const float* kptf = (const float*)d_in[0];
    const float* kptx = (const float*)d_in[1];
    const float* nbrf = (const float*)d_in[2];
    const float* nbrx = (const float*)d_in[3];
    const float* nbrn = (const float*)d_in[4];

    int prep_total = WB1_ELEMS + WB2_ELEMS + WCC_ELEMS + SMALL_FLOATS;
    ppf_prep<<<dim3((prep_total + 255) / 256), dim3(256), 0, stream>>>(
        (const float*)d_in[5],  (const float*)d_in[6],  (const float*)d_in[7],
        (const float*)d_in[8],  (const float*)d_in[9],  (const float*)d_in[10],
        (const float*)d_in[11], (const float*)d_in[12], (const float*)d_in[13],
        (const float*)d_in[14], (const float*)d_in[15], (const float*)d_in[16],
        (const float*)d_in[17], (const float*)d_in[18], (const float*)d_in[19],
        (const float*)d_in[20], (const float*)d_in[21], (const float*)d_in[22],
        (const float*)d_in[23], (const float*)d_in[24], (const float*)d_in[25],
        (const float*)d_in[26], (const float*)d_in[27], (const float*)d_in[28],
        (const float*)d_in[29], (const float*)d_in[30], d_ws);

    cc_gemm<<<dim3((NB * NN) / 64), dim3(256), 0, stream>>>(kptf, d_ws, (float*)d_out);

    ppf_main<<<dim3((NB * NN) / 4), dim3(256), 0, stream>>>(
        kptx, nbrf, nbrx, nbrn, d_ws, (float*)d_out);
}